// Round 9
// baseline (224.990 us; speedup 1.0000x reference)
//
#include <hip/hip_runtime.h>

// Dilate = 5x5 per-channel max filter, SAME padding, (64,384,384,3) f32.
// v9: copy-ubench shape — occupancy x small unsinkable load batches.
//   v1-v8 post-mortem: forcing per-wave depth (VGPR pipeline, volatile asm,
//   8/16-row global_load_lds rings with counted vmcnt) NEVER moved the
//   2.2-2.6 TB/s invariant; v8's nominal 110 KB/CU in flight was SLOWER.
//   The only proven 6.3 TB/s shape on this chip (m13 copy ubench) is:
//   full occupancy, persistent waves, each iteration a small batch of
//   independent loads with one consumer. This is that shape for dilate:
//   - 2048 blocks x 4 waves = 8192 waves = exactly 32/CU (8/SIMD),
//     launch_bounds(256,8) targets <=64 VGPR; no LDS, no asm, no barriers.
//   - wave task = (row, 60-col segment): load the word from all 5 window
//     rows (clamped) -> 5 INDEPENDENT loads, single common consumer (the
//     vertical max) -> scheduler cannot sink below depth 5. 32 waves x
//     5 KB = 160 KB/CU in flight at full residency.
//   - 15 tasks/wave = 3 consecutive rows x 5 segs of one image: 4/5 input
//     rows reuse L1 across tasks; 5x logical re-read served by L1/L2/L3
//     (input is L3-resident; verified absorption in v1-v8 FETCH counts).
//   - verbatim-verified pieces: v5 shuffle horizontal (absmax 0.0 x4),
//     row-clamp vertical padding, XCD chunking, nt stores.

#define Bn 64
#define H 384
#define ROWB 4608            // bytes per image row (384*3*4)
#define WF4 288              // float4 words per row
#define SEGS 5               // 5 x 60 = 300 >= 288 output words per row
#define TPW 15               // tasks per wave: 8192 waves x 15 = 122,880
#define NTHR 256             // 4 waves
#define NBLK 2048            // 8 blocks/CU exactly; divisible by 8 (XCD)
#define NEGINF (-3.402823466e+38f)

typedef float f32x4 __attribute__((ext_vector_type(4)));

__device__ __forceinline__ f32x4 max4(f32x4 a, f32x4 b) {
  f32x4 r;
  r.x = fmaxf(a.x, b.x); r.y = fmaxf(a.y, b.y);
  r.z = fmaxf(a.z, b.z); r.w = fmaxf(a.w, b.w);
  return r;
}

__global__ __launch_bounds__(NTHR, 8) void dilate5_kernel(
    const float* __restrict__ in, float* __restrict__ out) {
  const int wv = threadIdx.x >> 6;
  const int lane = threadIdx.x & 63;

  // XCD chunking: consecutive hw blockIdx round-robins XCDs; remap so each
  // XCD owns a contiguous slab (= 8 images) -> halo/re-read L2 locality.
  const int orig = blockIdx.x;
  const int bid = (orig & 7) * (NBLK / 8) + (orig >> 3);

  // Wave's 15 consecutive tasks: task tau -> (image b, row, segment).
  const int tau0 = (bid * 4 + wv) * TPW;

#pragma unroll
  for (int t = 0; t < TPW; ++t) {
    const int tau = tau0 + t;
    const int seg = tau % SEGS;
    const int rr = tau / SEGS;          // global row index across batch
    const int row = rr % H;
    const int b = rr / H;

    // strip geometry (v5-verified): lane owns word seg*60-2+lane
    const int col = seg * 60 - 2 + lane;
    const bool cvalid = (col >= 0) && (col < WF4);
    const int ccl = col < 0 ? 0 : (col > WF4 - 1 ? WF4 - 1 : col);
    const bool willstore = (lane >= 2) && (lane < 62) && (col < WF4);

    const char* __restrict__ imgb = (const char*)in + (size_t)b * H * ROWB;
    const size_t coff = (size_t)ccl * 16;

    // 5 independent loads (rows row-2..row+2, clamped: duplicate row is
    // identity under max). Single common consumer -> depth-5 guaranteed.
    int r0 = row - 2; r0 = r0 < 0 ? 0 : r0;
    int r1 = row - 1; r1 = r1 < 0 ? 0 : r1;
    int r3 = row + 1; r3 = r3 > H - 1 ? H - 1 : r3;
    int r4 = row + 2; r4 = r4 > H - 1 ? H - 1 : r4;
    f32x4 w0 = *reinterpret_cast<const f32x4*>(imgb + (size_t)r0 * ROWB + coff);
    f32x4 w1 = *reinterpret_cast<const f32x4*>(imgb + (size_t)r1 * ROWB + coff);
    f32x4 w2 = *reinterpret_cast<const f32x4*>(imgb + (size_t)row * ROWB + coff);
    f32x4 w3 = *reinterpret_cast<const f32x4*>(imgb + (size_t)r3 * ROWB + coff);
    f32x4 w4 = *reinterpret_cast<const f32x4*>(imgb + (size_t)r4 * ROWB + coff);

    // vertical 5-max
    f32x4 v = max4(max4(max4(w0, w1), max4(w2, w3)), w4);
    if (!cvalid) { v.x = NEGINF; v.y = NEGINF; v.z = NEGINF; v.w = NEGINF; }

    // horizontal 5-max, channel stride 3 (v5-verified formulas):
    // word c-2 contributes only .z/.w, word c+2 only .x/.y -> 12 shuffles.
    float Bx = __shfl_up(v.x, 1), By = __shfl_up(v.y, 1);
    float Bz = __shfl_up(v.z, 1), Bw = __shfl_up(v.w, 1);
    float Dx = __shfl_down(v.x, 1), Dy = __shfl_down(v.y, 1);
    float Dz = __shfl_down(v.z, 1), Dw = __shfl_down(v.w, 1);
    float Az = __shfl_up(v.z, 2), Aw = __shfl_up(v.w, 2);
    float Ex = __shfl_down(v.x, 2), Ey = __shfl_down(v.y, 2);
    f32x4 h;
    h.x = fmaxf(fmaxf(fmaxf(Az, By), fmaxf(v.x, v.w)), Dz);
    h.y = fmaxf(fmaxf(fmaxf(Aw, Bz), fmaxf(v.y, Dx)), Dw);
    h.z = fmaxf(fmaxf(fmaxf(Bx, Bw), fmaxf(v.z, Dy)), Ex);
    h.w = fmaxf(fmaxf(fmaxf(By, v.x), fmaxf(v.w, Dz)), Ey);

    if (willstore)
      __builtin_nontemporal_store(
          h, reinterpret_cast<f32x4*>((char*)out + (size_t)b * H * ROWB +
                                      (size_t)row * ROWB + (size_t)col * 16));
  }
}

extern "C" void kernel_launch(void* const* d_in, const int* in_sizes, int n_in,
                              void* d_out, int out_size, void* d_ws, size_t ws_size,
                              hipStream_t stream) {
  const float* images = (const float*)d_in[0];
  float* out = (float*)d_out;
  dilate5_kernel<<<NBLK, NTHR, 0, stream>>>(images, out);
}